// Round 7
// baseline (495.930 us; speedup 1.0000x reference)
//
#include <hip/hip_runtime.h>
#include <math.h>

// ============================================================================
// GeometricSuperpositionSearch — Cl(3,0) GA search, fp32.
// Basis order: [1, e1, e2, e3, e12, e13, e23, e123]
// Round 7: r5 scalar GEMM (pk reverted) + r6 LDS swizzle (0 conflicts) +
//   2-waves-per-row split: 512-thr blocks = 8 waves = 4 rows x 2 halves,
//   grid 1024 -> 32 waves/CU ceiling (was grid-capped at 16). Cross-wave
//   reductions via small LDS scratch.
// ============================================================================

#define NOISE_MODE 0
#define DEV static __device__ __forceinline__

constexpr int Bz = 512;
constexpr int Cz = 256;
constexpr int MIDz = 128;
constexpr int Hz = 8;
constexpr int Nz = 4096;   // B*H
constexpr int Az = 5;
constexpr int NOISE_PER_D = Nz * Az;   // 20480

// ---------------- workspace layout (float offsets) ----------------
constexpr size_t OFF_ROTH  = 0;                          // 8*8
constexpr size_t OFF_ROTA  = OFF_ROTH + 64;              // 5*8
constexpr size_t OFF_ROTC  = OFF_ROTA + 40;              // 256*8
constexpr size_t OFF_EXPL  = OFF_ROTC + 2048;            // 512
constexpr size_t OFF_HV    = OFF_EXPL + 512;             // 4096
constexpr size_t OFF_FIRST = OFF_HV + 4096;              // 4096 (int)
constexpr size_t OFF_WTP   = OFF_FIRST + 4096;           // [c][o] 256*128, nw folded
constexpr size_t OFF_WTD   = OFF_WTP + (size_t)Cz * MIDz;// [c][o] 256*256
constexpr size_t OFF_A     = OFF_WTD + (size_t)Cz * Cz;  // N*C*8 state buffer

// ---------------- Cl(3,0) geometric product ----------------
DEV void gp8(const float* a, const float* b, float* c) {
  c[0] = a[0]*b[0]+a[1]*b[1]+a[2]*b[2]+a[3]*b[3]-a[4]*b[4]-a[5]*b[5]-a[6]*b[6]-a[7]*b[7];
  c[1] = a[0]*b[1]+a[1]*b[0]-a[2]*b[4]-a[3]*b[5]+a[4]*b[2]+a[5]*b[3]-a[6]*b[7]-a[7]*b[6];
  c[2] = a[0]*b[2]+a[2]*b[0]+a[1]*b[4]-a[4]*b[1]-a[3]*b[6]+a[6]*b[3]+a[5]*b[7]+a[7]*b[5];
  c[3] = a[0]*b[3]+a[3]*b[0]+a[1]*b[5]-a[5]*b[1]+a[2]*b[6]-a[6]*b[2]-a[4]*b[7]-a[7]*b[4];
  c[4] = a[0]*b[4]+a[4]*b[0]+a[1]*b[2]-a[2]*b[1]-a[5]*b[6]+a[6]*b[5]+a[3]*b[7]+a[7]*b[3];
  c[5] = a[0]*b[5]+a[5]*b[0]+a[1]*b[3]-a[3]*b[1]+a[4]*b[6]-a[6]*b[4]-a[2]*b[7]-a[7]*b[2];
  c[6] = a[0]*b[6]+a[6]*b[0]+a[2]*b[3]-a[3]*b[2]-a[4]*b[5]+a[5]*b[4]+a[1]*b[7]+a[7]*b[1];
  c[7] = a[0]*b[7]+a[7]*b[0]+a[1]*b[6]+a[6]*b[1]+a[3]*b[4]+a[4]*b[3]-a[2]*b[5]-a[5]*b[2];
}

DEV void sandwich8(const float* R, const float* x, float* y) {
  float t[8];
  gp8(R, x, t);
  float Rr[8] = {R[0], R[1], R[2], R[3], -R[4], -R[5], -R[6], -R[7]};
  gp8(t, Rr, y);
}

DEV void rotor_from_bv(const float* bv, float* R) {
  float c4 = -0.5f * bv[0], c5 = -0.5f * bv[1], c6 = -0.5f * bv[2];
  float t = sqrtf(c4*c4 + c5*c5 + c6*c6);
  float sinc = (t < 1e-6f) ? (1.0f - t*t/6.0f) : (sinf(t)/t);
  R[0] = cosf(t); R[1] = 0.f; R[2] = 0.f; R[3] = 0.f;
  R[4] = sinc*c4; R[5] = sinc*c5; R[6] = sinc*c6; R[7] = 0.f;
}

// ---------------- threefry2x32, key = (0, 42) ----------------
DEV unsigned tf_rotl(unsigned v, int n) { return (v << n) | (v >> (32 - n)); }

DEV void threefry2x32(unsigned x0, unsigned x1, unsigned& o0, unsigned& o1) {
  const unsigned k0 = 0u, k1 = 42u;
  const unsigned k2 = k0 ^ k1 ^ 0x1BD11BDAu;
  x0 += k0; x1 += k1;
#define TF_R(r) { x0 += x1; x1 = tf_rotl(x1, r); x1 ^= x0; }
  TF_R(13) TF_R(15) TF_R(26) TF_R(6)
  x0 += k1; x1 += k2 + 1u;
  TF_R(17) TF_R(29) TF_R(16) TF_R(24)
  x0 += k2; x1 += k0 + 2u;
  TF_R(13) TF_R(15) TF_R(26) TF_R(6)
  x0 += k0; x1 += k1 + 3u;
  TF_R(17) TF_R(29) TF_R(16) TF_R(24)
  x0 += k1; x1 += k2 + 4u;
  TF_R(13) TF_R(15) TF_R(26) TF_R(6)
  x0 += k2; x1 += k0 + 5u;
#undef TF_R
  o0 = x0; o1 = x1;
}

DEV float erfinv32(float x) {
  float w = -log1pf(-x * x);
  float p;
  if (w < 5.0f) {
    w = w - 2.5f;
    p = 2.81022636e-08f;
    p = fmaf(p, w, 3.43273939e-07f);
    p = fmaf(p, w, -3.5233877e-06f);
    p = fmaf(p, w, -4.39150654e-06f);
    p = fmaf(p, w, 0.00021858087f);
    p = fmaf(p, w, -0.00125372503f);
    p = fmaf(p, w, -0.00417768164f);
    p = fmaf(p, w, 0.246640727f);
    p = fmaf(p, w, 1.50140941f);
  } else {
    w = sqrtf(w) - 3.0f;
    p = -0.000200214257f;
    p = fmaf(p, w, 0.000100950558f);
    p = fmaf(p, w, 0.00134934322f);
    p = fmaf(p, w, -0.00367342844f);
    p = fmaf(p, w, 0.00573950773f);
    p = fmaf(p, w, -0.0076224613f);
    p = fmaf(p, w, 0.00943887047f);
    p = fmaf(p, w, 1.00167406f);
    p = fmaf(p, w, 2.83297682f);
  }
  return p * x;
}

DEV float noise_val(int d, int r, int a) {
  unsigned idx = (unsigned)(d * NOISE_PER_D + r * Az + a);
  unsigned o0, o1, bits;
#if NOISE_MODE == 0
  threefry2x32(0u, idx, o0, o1);
  bits = o0 ^ o1;
#elif NOISE_MODE == 1
  const unsigned HALF = (unsigned)(3 * NOISE_PER_D) / 2u;
  unsigned j = (idx < HALF) ? idx : idx - HALF;
  threefry2x32(j, j + HALF, o0, o1);
  bits = (idx < HALF) ? o0 : o1;
#elif NOISE_MODE == 2
  threefry2x32(0u, idx, o0, o1);
  bits = o1;
#else
  threefry2x32(0u, idx, o0, o1);
  bits = o0;
#endif
  const float MINV = __uint_as_float(0xBF7FFFFFu);
  float f = __uint_as_float((bits >> 9) | 0x3F800000u) - 1.0f;
  float u = fmaxf(MINV, f * 2.0f + MINV);
  const float SQRT2 = __uint_as_float(0x3FB504F3u);
  return (SQRT2 * erfinv32(u)) * 0.3f;
}

DEV float gelu_tanh(float x) {
  float x3 = (x * x) * x;
  float t = tanhf(0.7978845608028654f * (x + 0.044715f * x3));
  return x * (0.5f * (1.0f + t));
}

// pred clinear + ggelu from swizzled LDS row; ONE output o per lane
DEV void pred_gemm1(const float4* __restrict__ X, int o, float invd,
                    const float* __restrict__ WtP, const float* __restrict__ plb,
                    float hh[8]) {
  float acc[8] = {0, 0, 0, 0, 0, 0, 0, 0};
#pragma unroll 2
  for (int c4 = 0; c4 < 64; c4++) {
#pragma unroll
    for (int k = 0; k < 4; k++) {
      float4 xa = X[(k << 6) + c4];
      float4 xb = X[Cz + (k << 6) + c4];
      float wv = WtP[(size_t)(4 * c4 + k) * MIDz + o];
      acc[0] = fmaf(wv, xa.x, acc[0]);
      acc[1] = fmaf(wv, xa.y, acc[1]);
      acc[2] = fmaf(wv, xa.z, acc[2]);
      acc[3] = fmaf(wv, xa.w, acc[3]);
      acc[4] = fmaf(wv, xb.x, acc[4]);
      acc[5] = fmaf(wv, xb.y, acc[5]);
      acc[6] = fmaf(wv, xb.z, acc[6]);
      acc[7] = fmaf(wv, xb.w, acc[7]);
    }
  }
  float nsq = 0.f;
#pragma unroll
  for (int dd = 0; dd < 8; dd++) {
    hh[dd] = fmaf(acc[dd], invd, plb[o * 8 + dd]);
    nsq += hh[dd] * hh[dd];
  }
  float nn = sqrtf(nsq + 1e-6f);
  float sc = gelu_tanh(nn) / (nn + 1e-6f);
#pragma unroll
  for (int dd = 0; dd < 8; dd++) hh[dd] *= sc;
}

// ============================================================================
// kernels
// ============================================================================

__global__ void k_prep(const float* __restrict__ hyp_bv, const float* __restrict__ act_bv,
                       const float* __restrict__ rot_bv, const float* __restrict__ plw,
                       const float* __restrict__ pnw, const float* __restrict__ dlw,
                       float* __restrict__ rotH, float* __restrict__ rotA,
                       float* __restrict__ rotC, float* __restrict__ hyp_val,
                       float* __restrict__ WtP, float* __restrict__ WtD) {
  int t = blockIdx.x * 256 + threadIdx.x;   // grid 256 -> 65536 threads
  if (t < Cz * Cz)   { int c = t >> 8, o = t & 255; WtD[t] = dlw[o * Cz + c]; }
  if (t < Cz * MIDz) { int c = t >> 7, o = t & 127; WtP[t] = plw[o * Cz + c] * pnw[c]; }
  if (t < Nz) hyp_val[t] = 0.f;
  if (t < 8) rotor_from_bv(hyp_bv + t * 3, rotH + t * 8);
  else if (t < 13) rotor_from_bv(act_bv + (t - 8) * 3, rotA + (t - 8) * 8);
  else if (t >= 16 && t < 16 + Cz) rotor_from_bv(rot_bv + (t - 16) * 3, rotC + (t - 16) * 8);
}

__global__ void k_explore(const float* __restrict__ state, const float* __restrict__ w1,
                          const float* __restrict__ b1, const float* __restrict__ w2,
                          const float* __restrict__ b2, float* __restrict__ explore) {
  int b = blockIdx.x, c = threadIdx.x;
  const float4* xp = (const float4*)(state + ((size_t)b * Cz + c) * 8);
  float4 lo = xp[0], hi = xp[1];
  float g0 = lo.x * lo.x;
  float g1 = lo.y * lo.y + lo.z * lo.z + lo.w * lo.w;
  float g2 = hi.x * hi.x + hi.y * hi.y + hi.z * hi.z;
  float g3 = hi.w * hi.w;
  __shared__ float4 sm[256];
  sm[c] = make_float4(sqrtf(g0 + 1e-12f), sqrtf(g1 + 1e-12f),
                      sqrtf(g2 + 1e-12f), sqrtf(g3 + 1e-12f));
  __syncthreads();
  for (int s = 128; s > 0; s >>= 1) {
    if (c < s) {
      sm[c].x += sm[c + s].x; sm[c].y += sm[c + s].y;
      sm[c].z += sm[c + s].z; sm[c].w += sm[c + s].w;
    }
    __syncthreads();
  }
  if (c == 0) {
    float pooled[4] = {sm[0].x / 256.f, sm[0].y / 256.f, sm[0].z / 256.f, sm[0].w / 256.f};
    float theta = b2[0];
    for (int j = 0; j < 32; j++) {
      float hj = b1[j];
      for (int g = 0; g < 4; g++) hj = fmaf(pooled[g], w1[g * 32 + j], hj);
      hj = fmaxf(hj, 0.f);
      theta = fmaf(hj, w2[j], theta);
    }
    explore[b] = fabsf(tanhf(theta));
  }
}

// fused step: 512 threads = 8 waves = 4 rows x 2 halves.
// Row wr = wave>>1, half ww = wave&1. Lane l of half ww owns channels/outputs
// with k = 2*ww + k2 (k2 in {0,1}): channel c = 4l+k, dyn output o = 4l+k.
// Swizzled LDS slot for c = 4*c4+k is (k<<6)+c4.
__global__ __launch_bounds__(512, 8) void k_step(
    const float* __restrict__ src, float* __restrict__ dst, int apply_hyp,
    int dstep, int do_term,
    const float* __restrict__ rotH, const float* __restrict__ rotA,
    const float* __restrict__ rotC, const float* __restrict__ WtP,
    const float* __restrict__ plb, const float* __restrict__ pw,
    const float* __restrict__ pb, const float* __restrict__ vw,
    const float* __restrict__ vb, const float* __restrict__ dnw,
    const float* __restrict__ WtD, const float* __restrict__ dlb,
    const float* __restrict__ rw, const float* __restrict__ rb,
    const float* __restrict__ explore, float* __restrict__ hyp_val,
    int* __restrict__ first_act, float discf, float termdisc) {
  __shared__ float4 xs[4][2 * Cz];      // 32 KB row tiles
  __shared__ float rnorm[4][2][2];      // nsum, bsum
  __shared__ float rpol[4][2][Az];
  __shared__ float rdy[4][2];           // dyn norm
  __shared__ float rrw[4][2];           // reward
  __shared__ float rts[4][2];           // term norm
  __shared__ float rv[4][2];            // term value
  int wave = threadIdx.x >> 6, l = threadIdx.x & 63;
  int wr = wave >> 1, ww = wave & 1;
  int r = blockIdx.x * 4 + wr;
  int b = r >> 3, h = r & 7;
  float4* X = xs[wr];
  const float* row = apply_hyp ? (src + (size_t)b * Cz * 8) : (src + (size_t)r * Cz * 8);
  float Rh[8];
  if (apply_hyp) {
#pragma unroll
    for (int i = 0; i < 8; i++) Rh[i] = rotH[h * 8 + i];
  }
  // ---- S0: stage own 2 channels + norm partials ----
  float nsum = 0.f, bsum = 0.f;
#pragma unroll
  for (int k2 = 0; k2 < 2; k2++) {
    int k = 2 * ww + k2;
    int c = 4 * l + k;
    const float4* xp = (const float4*)(row + (size_t)c * 8);
    float4 v0 = xp[0], v1 = xp[1];
    float x[8] = {v0.x, v0.y, v0.z, v0.w, v1.x, v1.y, v1.z, v1.w};
    if (apply_hyp) {
      float t[8];
      sandwich8(Rh, x, t);
#pragma unroll
      for (int i = 0; i < 8; i++) x[i] = t[i];
    }
    float ss = 0.f;
#pragma unroll
    for (int i = 0; i < 8; i++) ss += x[i] * x[i];
    nsum += sqrtf(ss + 1e-6f);
    bsum += x[4] * x[4] + x[5] * x[5] + x[6] * x[6];
    int sl = (k << 6) + l;
    X[sl]      = make_float4(x[0], x[1], x[2], x[3]);
    X[Cz + sl] = make_float4(x[4], x[5], x[6], x[7]);
  }
#pragma unroll
  for (int m = 1; m < 64; m <<= 1) {
    nsum += __shfl_xor(nsum, m);
    bsum += __shfl_xor(bsum, m);
  }
  if (l == 0) { rnorm[wr][ww][0] = nsum; rnorm[wr][ww][1] = bsum; }
  __syncthreads();

  // ---- S1: pred GEMM (1 output/lane) + policy partials ----
  float nT = rnorm[wr][0][0] + rnorm[wr][1][0];
  float bT = rnorm[wr][0][1] + rnorm[wr][1][1];
  float invd = 1.0f / (nT / 256.f + 1e-6f);
  float bv_e = bT / 256.f;
  int o1 = 64 * ww + l;
  float hh[8];
  pred_gemm1(X, o1, invd, WtP, plb, hh);
  float pol[Az] = {0, 0, 0, 0, 0};
#pragma unroll
  for (int k = 0; k < 3; k++) {
    float v = hh[1 + k];
    const float* pwj = pw + (size_t)(o1 * 3 + k) * Az;
#pragma unroll
    for (int a = 0; a < Az; a++) pol[a] = fmaf(v, pwj[a], pol[a]);
  }
#pragma unroll
  for (int m = 1; m < 64; m <<= 1) {
#pragma unroll
    for (int a = 0; a < Az; a++) pol[a] += __shfl_xor(pol[a], m);
  }
  if (l < Az) rpol[wr][ww][l] = pol[l];
  __syncthreads();

  // ---- S2: argmax (redundant per wave) + dyn sandwich + dyn-norm partial ----
  float coef = explore[b] * bv_e;
  float sa = -INFINITY;
  if (l < Az) {
    float pfull = rpol[wr][0][l] + rpol[wr][1][l] + pb[l];
    sa = pfull + coef * noise_val(dstep, r, l);
  }
  int best = 0;
  float bs = -INFINITY;
#pragma unroll
  for (int a = 0; a < Az; a++) {
    float s = __shfl(sa, a);
    if (s > bs) { bs = s; best = a; }
  }
  if (dstep == 0 && ww == 0 && l == 0) first_act[r] = best;

  float Ra[8];
#pragma unroll
  for (int i = 0; i < 8; i++) Ra[i] = rotA[best * 8 + i];
  float y[2][8];
  float nsum2 = 0.f;
#pragma unroll
  for (int k2 = 0; k2 < 2; k2++) {
    int k = 2 * ww + k2;
    int sl = (k << 6) + l;
    float4 xa = X[sl], xb = X[Cz + sl];
    float x[8] = {xa.x, xa.y, xa.z, xa.w, xb.x, xb.y, xb.z, xb.w};
    sandwich8(Ra, x, y[k2]);
    float ss = 0.f;
#pragma unroll
    for (int i = 0; i < 8; i++) ss += y[k2][i] * y[k2][i];
    nsum2 += sqrtf(ss + 1e-6f);
  }
#pragma unroll
  for (int m = 1; m < 64; m <<= 1) nsum2 += __shfl_xor(nsum2, m);
  if (l == 0) rdy[wr][ww] = nsum2;
  __syncthreads();   // all X reads (pred + sandwich) complete

  // ---- S3: ggelu + channel rotor -> h' into X ----
  float invd2 = 1.0f / ((rdy[wr][0] + rdy[wr][1]) / 256.f + 1e-6f);
#pragma unroll
  for (int k2 = 0; k2 < 2; k2++) {
    int k = 2 * ww + k2;
    int c = 4 * l + k;
    float sc = dnw[c] * invd2;
    float hch[8];
    float nsq = 0.f;
#pragma unroll
    for (int i = 0; i < 8; i++) { hch[i] = y[k2][i] * sc; nsq += hch[i] * hch[i]; }
    float nn = sqrtf(nsq + 1e-6f);
    float ge = gelu_tanh(nn) / (nn + 1e-6f);
#pragma unroll
    for (int i = 0; i < 8; i++) hch[i] *= ge;
    float Rc[8];
    const float4* rp = (const float4*)(rotC + (size_t)c * 8);
    float4 r0 = rp[0], r1 = rp[1];
    Rc[0] = r0.x; Rc[1] = r0.y; Rc[2] = r0.z; Rc[3] = r0.w;
    Rc[4] = r1.x; Rc[5] = r1.y; Rc[6] = r1.z; Rc[7] = r1.w;
    float hp[8];
    sandwich8(Rc, hch, hp);
    int sl = (k << 6) + l;
    X[sl]      = make_float4(hp[0], hp[1], hp[2], hp[3]);
    X[Cz + sl] = make_float4(hp[4], hp[5], hp[6], hp[7]);
  }
  __syncthreads();

  // ---- S4: dyn GEMM, 2 outputs/lane: o = 4l + 2ww + k2 ----
  float acc[2][8];
  int ob = 4 * l + 2 * ww;
#pragma unroll
  for (int k2 = 0; k2 < 2; k2++) {
#pragma unroll
    for (int dd = 0; dd < 8; dd++) acc[k2][dd] = y[k2][dd] + dlb[(ob + k2) * 8 + dd];
  }
#pragma unroll 2
  for (int c4 = 0; c4 < 64; c4++) {
#pragma unroll
    for (int k = 0; k < 4; k++) {
      float4 xa = X[(k << 6) + c4];
      float4 xb = X[Cz + (k << 6) + c4];
      float2 w2 = *(const float2*)&WtD[(size_t)(4 * c4 + k) * Cz + ob];
      acc[0][0] = fmaf(w2.x, xa.x, acc[0][0]);
      acc[0][1] = fmaf(w2.x, xa.y, acc[0][1]);
      acc[0][2] = fmaf(w2.x, xa.z, acc[0][2]);
      acc[0][3] = fmaf(w2.x, xa.w, acc[0][3]);
      acc[0][4] = fmaf(w2.x, xb.x, acc[0][4]);
      acc[0][5] = fmaf(w2.x, xb.y, acc[0][5]);
      acc[0][6] = fmaf(w2.x, xb.z, acc[0][6]);
      acc[0][7] = fmaf(w2.x, xb.w, acc[0][7]);
      acc[1][0] = fmaf(w2.y, xa.x, acc[1][0]);
      acc[1][1] = fmaf(w2.y, xa.y, acc[1][1]);
      acc[1][2] = fmaf(w2.y, xa.z, acc[1][2]);
      acc[1][3] = fmaf(w2.y, xa.w, acc[1][3]);
      acc[1][4] = fmaf(w2.y, xb.x, acc[1][4]);
      acc[1][5] = fmaf(w2.y, xb.y, acc[1][5]);
      acc[1][6] = fmaf(w2.y, xb.z, acc[1][6]);
      acc[1][7] = fmaf(w2.y, xb.w, acc[1][7]);
    }
  }

  // ---- reward partial (+ store / terminal) ----
  float rsum = fmaf(acc[0][0], rw[ob], acc[1][0] * rw[ob + 1]);
#pragma unroll
  for (int m = 1; m < 64; m <<= 1) rsum += __shfl_xor(rsum, m);
  if (l == 0) rrw[wr][ww] = rsum;

  if (!do_term) {
    float* drow = dst + (size_t)r * Cz * 8;
#pragma unroll
    for (int k2 = 0; k2 < 2; k2++) {
      float4* op = (float4*)(drow + (size_t)(ob + k2) * 8);
      op[0] = make_float4(acc[k2][0], acc[k2][1], acc[k2][2], acc[k2][3]);
      op[1] = make_float4(acc[k2][4], acc[k2][5], acc[k2][6], acc[k2][7]);
    }
    __syncthreads();
    if (ww == 0 && l == 0)
      hyp_val[r] += discf * (rrw[wr][0] + rrw[wr][1] + rb[0]);
  } else {
    __syncthreads();   // dyn-GEMM X reads + rrw published
    // write ns into X (slots for c = ob+k2 -> k = 2ww+k2) + term norm partial
    float tsum = 0.f;
#pragma unroll
    for (int k2 = 0; k2 < 2; k2++) {
      float ss = 0.f;
#pragma unroll
      for (int dd = 0; dd < 8; dd++) ss += acc[k2][dd] * acc[k2][dd];
      tsum += sqrtf(ss + 1e-6f);
      int sl = ((2 * ww + k2) << 6) + l;
      X[sl]      = make_float4(acc[k2][0], acc[k2][1], acc[k2][2], acc[k2][3]);
      X[Cz + sl] = make_float4(acc[k2][4], acc[k2][5], acc[k2][6], acc[k2][7]);
    }
#pragma unroll
    for (int m = 1; m < 64; m <<= 1) tsum += __shfl_xor(tsum, m);
    if (l == 0) rts[wr][ww] = tsum;
    __syncthreads();
    float invd3 = 1.0f / ((rts[wr][0] + rts[wr][1]) / 256.f + 1e-6f);
    float th[8];
    pred_gemm1(X, o1, invd3, WtP, plb, th);
    float v = th[0] * vw[o1];
#pragma unroll
    for (int m = 1; m < 64; m <<= 1) v += __shfl_xor(v, m);
    if (l == 0) rv[wr][ww] = v;
    __syncthreads();
    if (ww == 0 && l == 0)
      hyp_val[r] += discf * (rrw[wr][0] + rrw[wr][1] + rb[0])
                  + termdisc * (rv[wr][0] + rv[wr][1] + vb[0]);
  }
}

__global__ void k_out(const float* __restrict__ hyp_val, const int* __restrict__ first_act,
                      float* __restrict__ out) {
  int b = blockIdx.x * blockDim.x + threadIdx.x;
  if (b >= Bz) return;
  float hv[Hz];
  float m = -INFINITY;
#pragma unroll
  for (int h = 0; h < Hz; h++) { hv[h] = hyp_val[b * Hz + h]; m = fmaxf(m, hv[h]); }
  float e[Hz];
  float se = 0.f;
#pragma unroll
  for (int h = 0; h < Hz; h++) { e[h] = expf(hv[h] - m); se += e[h]; }
  float ap[Az] = {0, 0, 0, 0, 0};
#pragma unroll
  for (int h = 0; h < Hz; h++) ap[first_act[b * Hz + h]] += e[h] / se;
  float tot = 0.f;
#pragma unroll
  for (int a = 0; a < Az; a++) tot += ap[a];
  float dn = fmaxf(tot, 1e-8f);
#pragma unroll
  for (int a = 0; a < Az; a++) out[b * Az + a] = ap[a] / dn;
}

// ============================================================================

extern "C" void kernel_launch(void* const* d_in, const int* in_sizes, int n_in,
                              void* d_out, int out_size, void* d_ws, size_t ws_size,
                              hipStream_t stream) {
  const float* state      = (const float*)d_in[0];
  const float* hyp_bv     = (const float*)d_in[1];
  const float* sp_w1      = (const float*)d_in[2];
  const float* sp_b1      = (const float*)d_in[3];
  const float* sp_w2      = (const float*)d_in[4];
  const float* sp_b2      = (const float*)d_in[5];
  const float* p_norm_w   = (const float*)d_in[6];
  const float* p_lin_w    = (const float*)d_in[7];
  const float* p_lin_b    = (const float*)d_in[8];
  const float* p_vw       = (const float*)d_in[9];
  const float* p_vb       = (const float*)d_in[10];
  const float* p_pw       = (const float*)d_in[11];
  const float* p_pb       = (const float*)d_in[12];
  const float* act_bv     = (const float*)d_in[13];
  const float* d_norm_w   = (const float*)d_in[14];
  const float* d_rotor_bv = (const float*)d_in[15];
  const float* d_lin_w    = (const float*)d_in[16];
  const float* d_lin_b    = (const float*)d_in[17];
  const float* d_rw       = (const float*)d_in[18];
  const float* d_rb       = (const float*)d_in[19];
  float* out = (float*)d_out;
  float* ws  = (float*)d_ws;

  float* rotH    = ws + OFF_ROTH;
  float* rotA    = ws + OFF_ROTA;
  float* rotC    = ws + OFF_ROTC;
  float* explore = ws + OFF_EXPL;
  float* hyp_val = ws + OFF_HV;
  int*   first   = (int*)(ws + OFF_FIRST);
  float* WtP     = ws + OFF_WTP;
  float* WtD     = ws + OFF_WTD;
  float* bufA    = ws + OFF_A;

  k_prep<<<256, 256, 0, stream>>>(hyp_bv, act_bv, d_rotor_bv, p_lin_w, p_norm_w,
                                  d_lin_w, rotH, rotA, rotC, hyp_val, WtP, WtD);
  k_explore<<<Bz, 256, 0, stream>>>(state, sp_w1, sp_b1, sp_w2, sp_b2, explore);

  const float d1 = 0.99f, d2 = 0.99f * 0.99f, d3 = 0.99f * 0.99f * 0.99f;
  // d=0: state(+hyp) -> bufA
  k_step<<<Nz / 4, 512, 0, stream>>>(state, bufA, 1, 0, 0, rotH, rotA, rotC, WtP,
                                     p_lin_b, p_pw, p_pb, p_vw, p_vb, d_norm_w, WtD,
                                     d_lin_b, d_rw, d_rb, explore, hyp_val, first,
                                     1.0f, 0.f);
  // d=1: bufA in-place
  k_step<<<Nz / 4, 512, 0, stream>>>(bufA, bufA, 0, 1, 0, rotH, rotA, rotC, WtP,
                                     p_lin_b, p_pw, p_pb, p_vw, p_vb, d_norm_w, WtD,
                                     d_lin_b, d_rw, d_rb, explore, hyp_val, first,
                                     d1, 0.f);
  // d=2: no store + fused terminal value
  k_step<<<Nz / 4, 512, 0, stream>>>(bufA, bufA, 0, 2, 1, rotH, rotA, rotC, WtP,
                                     p_lin_b, p_pw, p_pb, p_vw, p_vb, d_norm_w, WtD,
                                     d_lin_b, d_rw, d_rb, explore, hyp_val, first,
                                     d2, d3);
  k_out<<<2, 256, 0, stream>>>(hyp_val, first, out);
}